// Round 27
// baseline (532.436 us; speedup 1.0000x reference)
//
#include <hip/hip_runtime.h>
#include <hip/hip_fp16.h>
#include <math.h>

#define N_NODES 50000
#define N_EDGES 800000
#define NB 256
#define AD 39
#define BD 10
#define H 128
#define HEADS 4
#define HD 32
#define LAYERS 3
#define TD 128
#define NBUCK 196
#define EPB 4096

typedef _Float16 f16x8 __attribute__((ext_vector_type(8)));
typedef float f32x4 __attribute__((ext_vector_type(4)));

__device__ __forceinline__ float silu_f(float x) { return x / (1.f + __expf(-x)); }

// ---------------------------------------------------------------------------
// Generic vector GEMM (only used for the atom embedding, K=39)
// ---------------------------------------------------------------------------
__device__ __forceinline__ void fma_rank1(float acc[8][4], float4 aL, float4 aH, float4 w)
{
    float ar[8] = {aL.x, aL.y, aL.z, aL.w, aH.x, aH.y, aH.z, aH.w};
    float wr[4] = {w.x, w.y, w.z, w.w};
#pragma unroll
    for (int r = 0; r < 8; r++)
#pragma unroll
        for (int j = 0; j < 4; j++) acc[r][j] += ar[r] * wr[j];
}

template<int KT>
__global__ __launch_bounds__(256) void gemm128(
    const float* __restrict__ A, const float* __restrict__ W,
    const float* __restrict__ bias, float* __restrict__ out,
    int Nrows, int ldw)
{
    __shared__ float As[KT * 68];
    const int tid = threadIdx.x;
    const int rowBase = blockIdx.x * 64;

    for (int idx = tid; idx < 64 * KT; idx += 256) {
        int row = idx / KT;
        int k = idx - row * KT;
        int n = rowBase + row;
        As[k * 68 + row] = (n < Nrows) ? A[(size_t)n * KT + k] : 0.f;
    }
    __syncthreads();

    const int c0 = (tid & 31) * 4;
    const int n0 = (tid >> 5) * 8;

    float acc[8][4];
#pragma unroll
    for (int r = 0; r < 8; r++)
#pragma unroll
        for (int j = 0; j < 4; j++) acc[r][j] = 0.f;

    const float* wp = W + c0;
    int k = 0;
    for (; k + 4 <= KT; k += 4) {
        float4 w0 = *(const float4*)&wp[(size_t)(k + 0) * ldw];
        float4 w1 = *(const float4*)&wp[(size_t)(k + 1) * ldw];
        float4 w2 = *(const float4*)&wp[(size_t)(k + 2) * ldw];
        float4 w3 = *(const float4*)&wp[(size_t)(k + 3) * ldw];
        float4 aL0 = *(const float4*)&As[(k + 0) * 68 + n0];
        float4 aH0 = *(const float4*)&As[(k + 0) * 68 + n0 + 4];
        float4 aL1 = *(const float4*)&As[(k + 1) * 68 + n0];
        float4 aH1 = *(const float4*)&As[(k + 1) * 68 + n0 + 4];
        float4 aL2 = *(const float4*)&As[(k + 2) * 68 + n0];
        float4 aH2 = *(const float4*)&As[(k + 2) * 68 + n0 + 4];
        float4 aL3 = *(const float4*)&As[(k + 3) * 68 + n0];
        float4 aH3 = *(const float4*)&As[(k + 3) * 68 + n0 + 4];
        fma_rank1(acc, aL0, aH0, w0);
        fma_rank1(acc, aL1, aH1, w1);
        fma_rank1(acc, aL2, aH2, w2);
        fma_rank1(acc, aL3, aH3, w3);
    }
    for (; k < KT; ++k) {
        float4 w0 = *(const float4*)&wp[(size_t)k * ldw];
        float4 aL = *(const float4*)&As[k * 68 + n0];
        float4 aH = *(const float4*)&As[k * 68 + n0 + 4];
        fma_rank1(acc, aL, aH, w0);
    }

    float4 bv = make_float4(0.f, 0.f, 0.f, 0.f);
    if (bias) bv = *(const float4*)&bias[c0];

#pragma unroll
    for (int r = 0; r < 8; r++) {
        int n = rowBase + n0 + r;
        if (n >= Nrows) break;
        float4 o;
        o.x = acc[r][0] + bv.x;
        o.y = acc[r][1] + bv.y;
        o.z = acc[r][2] + bv.z;
        o.w = acc[r][3] + bv.w;
        *(float4*)&out[(size_t)n * H + c0] = o;
    }
}

// ---------------------------------------------------------------------------
// Merged setup + weight packing:
//   block 0       : edge-path fold (mc)
//   block 1       : gptr bsearch
//   blocks 2..257 : time embedding
//   blocks 258+   : w16 (lin_W x3 + out_W) and np W1/W2/W3pad fragments
// ---------------------------------------------------------------------------
__global__ __launch_bounds__(256) void setup_all(
    const float* __restrict__ edge_W, const float* __restrict__ att_edge,
    const float* __restrict__ bond_W, const float* __restrict__ bond_b,
    float* __restrict__ mc,
    const int* __restrict__ batch, int* __restrict__ gptr,
    const int* __restrict__ t,
    const float* __restrict__ W1, const float* __restrict__ b1,
    const float* __restrict__ W2, const float* __restrict__ b2,
    float* __restrict__ t_emb,
    const float* __restrict__ lin_W, const float* __restrict__ out_W,
    const float* __restrict__ npW1, const float* __restrict__ npW2,
    const float* __restrict__ npW3,
    __half* __restrict__ w16, __half* __restrict__ wnp)
{
    const int b = blockIdx.x;
    const int tid = threadIdx.x;
    if (b == 0) {
        __shared__ float bl[LAYERS][H][4];
        for (int task = tid; task < LAYERS * H; task += 256) {
            int l = task / H, k = task % H;
#pragma unroll
            for (int hh = 0; hh < 4; hh++) {
                float s = 0.f;
                for (int d = 0; d < HD; d++)
                    s += edge_W[(size_t)l * H * H + k * H + hh * HD + d] *
                         att_edge[l * H + hh * HD + d];
                bl[l][k][hh] = s;
            }
        }
        __syncthreads();
        if (tid < LAYERS * BD * 4) {
            int l = tid / (BD * 4), r = tid % (BD * 4), j = r / 4, hh = r % 4;
            float s = 0.f;
            for (int k = 0; k < H; k++) s += bond_W[j * H + k] * bl[l][k][hh];
            mc[l * 44 + j * 4 + hh] = s;
        }
        if (tid >= 128 && tid < 128 + LAYERS * 4) {
            int r = tid - 128, l = r / 4, hh = r % 4;
            float s = 0.f;
            for (int k = 0; k < H; k++) s += bond_b[k] * bl[l][k][hh];
            mc[l * 44 + 40 + hh] = s;
        }
    } else if (b == 1) {
        for (int g = tid; g <= NB; g += 256) {
            int lo = 0, hi = N_NODES;
            while (lo < hi) {
                int mid = (lo + hi) >> 1;
                if (batch[mid] < g) lo = mid + 1; else hi = mid;
            }
            gptr[g] = lo;
        }
    } else if (b < NB + 2) {
        int g = b - 2;
        int c = tid & 127;
        float tf = (float)t[g];
        __shared__ float emb[TD], z[H];
        int k = c & 63;
        float f = __expf(-9.210340371976184f * (float)k / 63.0f);
        float e = tf * f;
        emb[c] = (c < 64) ? sinf(e) : cosf(e);
        __syncthreads();
        float a1 = b1[c];
        for (int kk = 0; kk < TD; kk++) a1 += emb[kk] * W1[kk * H + c];
        z[c] = silu_f(a1);
        __syncthreads();
        float a2 = b2[c];
        for (int kk = 0; kk < H; kk++) a2 += z[kk] * W2[kk * H + c];
        t_emb[g * H + c] = a2;
    } else {
        int idx = (b - (NB + 2)) * 256 + tid;
        if (idx < 4 * H * H) {
            int mat = idx >> 14;
            int rem = idx & 16383;
            int k = rem >> 7;
            int n = rem & 127;
            const float* src = (mat < 3) ? (lin_W + (size_t)mat * H * H) : out_W;
            float v = src[(size_t)k * H + n];
            int ks = k >> 5, kr = k & 31;
            int lane = ((kr >> 3) << 4) | (n & 15);
            int j = kr & 7;
            int nb = n >> 4;
            w16[(size_t)mat * 16384 + (((ks * 8 + nb) * 64 + lane) << 3) + j] = __float2half(v);
            return;
        }
        int r = idx - 4 * H * H;
        if (r < 2 * H * H) {
            int mat = r >> 14;
            int rem = r & 16383;
            int k = rem >> 7;
            int n = rem & 127;
            const float* src = mat ? npW2 : npW1;
            float v = src[(size_t)k * H + n];
            int ks = k >> 5, kr = k & 31;
            int lane = ((kr >> 3) << 4) | (n & 15);
            int j = kr & 7;
            int nb = n >> 4;
            wnp[(size_t)mat * 16384 + (((ks * 8 + nb) * 64 + lane) << 3) + j] = __float2half(v);
            return;
        }
        r -= 2 * H * H;
        if (r >= H * 48) return;
        int k = r / 48;
        int n = r - k * 48;
        float v = (n < AD) ? npW3[(size_t)k * AD + n] : 0.f;
        int ks = k >> 5, kr = k & 31;
        int lane = ((kr >> 3) << 4) | (n & 15);
        int j = kr & 7;
        int nb = n >> 4;
        wnp[32768 + (((ks * 3 + nb) * 64 + lane) << 3) + j] = __float2half(v);
    }
}

// ---------------------------------------------------------------------------
// MFMA GEMM with fused BN-apply staging and fused attention-score epilogue.
// ---------------------------------------------------------------------------
__global__ __launch_bounds__(256) void gemm_mfma_bn(
    const float* __restrict__ A,
    const __half* __restrict__ agg, const float* __restrict__ scale,
    const float* __restrict__ shift, float* __restrict__ hio,
    const __half* __restrict__ wfrag, const float* __restrict__ bias,
    float* __restrict__ out32, __half* __restrict__ out16,
    const float* __restrict__ attS, const float* __restrict__ attD,
    float* __restrict__ sS, float* __restrict__ sD, int Nrows)
{
    __shared__ __half Ah[64 * 136];
    const int tid = threadIdx.x;
    const int rowBase = blockIdx.x * 64;

    for (int idx = tid; idx < 64 * 32; idx += 256) {
        int row = idx >> 5;
        int kq = (idx & 31) * 4;
        int n = rowBase + row;
        float4 v = make_float4(0.f, 0.f, 0.f, 0.f);
        if (n < Nrows) {
            if (agg) {
                uint2 u = *(const uint2*)&agg[(size_t)n * H + kq];
                float2 lo = __half22float2(*(__half2*)&u.x);
                float2 hi = __half22float2(*(__half2*)&u.y);
                float4 sc = *(const float4*)&scale[kq];
                float4 sh = *(const float4*)&shift[kq];
                float4 hv = *(const float4*)&hio[(size_t)n * H + kq];
                v.x = fmaxf(lo.x * sc.x + sh.x, 0.f) + hv.x;
                v.y = fmaxf(lo.y * sc.y + sh.y, 0.f) + hv.y;
                v.z = fmaxf(hi.x * sc.z + sh.z, 0.f) + hv.z;
                v.w = fmaxf(hi.y * sc.w + sh.w, 0.f) + hv.w;
                *(float4*)&hio[(size_t)n * H + kq] = v;
            } else {
                v = *(const float4*)&A[(size_t)n * H + kq];
            }
        }
        __half2 a = __floats2half2_rn(v.x, v.y);
        __half2 b = __floats2half2_rn(v.z, v.w);
        *(uint2*)&Ah[row * 136 + kq] = make_uint2(*(unsigned*)&a, *(unsigned*)&b);
    }
    __syncthreads();

    const int wave = tid >> 6;
    const int lane = tid & 63;
    const int lrow = lane & 15;
    const int lgrp = lane >> 4;

    f16x8 bf[4][2];
#pragma unroll
    for (int ks = 0; ks < 4; ks++)
#pragma unroll
        for (int nt = 0; nt < 2; nt++) {
            int nb = wave * 2 + nt;
            bf[ks][nt] = *(const f16x8*)&wfrag[(((ks * 8 + nb) * 64 + lane) << 3)];
        }

    f32x4 acc[4][2];
#pragma unroll
    for (int mt = 0; mt < 4; mt++)
#pragma unroll
        for (int nt = 0; nt < 2; nt++) acc[mt][nt] = (f32x4){0.f, 0.f, 0.f, 0.f};

#pragma unroll
    for (int ks = 0; ks < 4; ks++) {
#pragma unroll
        for (int mt = 0; mt < 4; mt++) {
            f16x8 af = *(const f16x8*)&Ah[(mt * 16 + lrow) * 136 + ks * 32 + lgrp * 8];
            acc[mt][0] = __builtin_amdgcn_mfma_f32_16x16x32_f16(af, bf[ks][0], acc[mt][0], 0, 0, 0);
            acc[mt][1] = __builtin_amdgcn_mfma_f32_16x16x32_f16(af, bf[ks][1], acc[mt][1], 0, 0, 0);
        }
    }

    const int col0 = wave * 32 + lrow;
    const int col1 = col0 + 16;
    float b0 = bias ? bias[col0] : 0.f;
    float b1 = bias ? bias[col1] : 0.f;
    float aS0 = 0.f, aS1 = 0.f, aD0 = 0.f, aD1 = 0.f;
    if (sS) {
        aS0 = attS[col0]; aS1 = attS[col1];
        aD0 = attD[col0]; aD1 = attD[col1];
    }

#pragma unroll
    for (int mt = 0; mt < 4; mt++) {
#pragma unroll
        for (int reg = 0; reg < 4; reg++) {
            int row = rowBase + mt * 16 + lgrp * 4 + reg;
            float v0 = acc[mt][0][reg] + b0;
            float v1 = acc[mt][1][reg] + b1;
            if (row < Nrows) {
                if (out16) {
                    out16[(size_t)row * H + col0] = __float2half(v0);
                    out16[(size_t)row * H + col1] = __float2half(v1);
                } else {
                    out32[(size_t)row * H + col0] = v0;
                    out32[(size_t)row * H + col1] = v1;
                }
            }
            if (sS) {
                float ps = v0 * aS0 + v1 * aS1;
                float pd = v0 * aD0 + v1 * aD1;
#pragma unroll
                for (int off = 8; off >= 1; off >>= 1) {
                    ps += __shfl_xor(ps, off, 16);
                    pd += __shfl_xor(pd, off, 16);
                }
                if (lrow == 0 && row < Nrows) {
                    sS[row * 4 + wave] = ps;
                    sD[row * 4 + wave] = pd;
                }
            }
        }
    }
}

// ---------------------------------------------------------------------------
// Fused noise-prediction head, fully MFMA (z1, z2, out); single Ah buffer.
// ---------------------------------------------------------------------------
__global__ __launch_bounds__(256) void np_fused_mfma(
    const float* __restrict__ nf, const int* __restrict__ batch,
    const float* __restrict__ tgW, const __half* __restrict__ wnp,
    const float* __restrict__ npb2, const float* __restrict__ npb3,
    float* __restrict__ out, int Nrows)
{
    __shared__ __half Ah[64 * 136];
    const int tid = threadIdx.x;
    const int rowBase = blockIdx.x * 64;

    for (int idx = tid; idx < 64 * 32; idx += 256) {
        int row = idx >> 5;
        int kq = (idx & 31) * 4;
        int n = rowBase + row;
        float4 v = make_float4(0.f, 0.f, 0.f, 0.f);
        if (n < Nrows) v = *(const float4*)&nf[(size_t)n * H + kq];
        __half2 a = __floats2half2_rn(v.x, v.y);
        __half2 b = __floats2half2_rn(v.z, v.w);
        *(uint2*)&Ah[row * 136 + kq] = make_uint2(*(unsigned*)&a, *(unsigned*)&b);
    }
    __syncthreads();

    const int wave = tid >> 6;
    const int lane = tid & 63;
    const int lrow = lane & 15;
    const int lgrp = lane >> 4;

    f32x4 acc[4][2];

    // ---- GEMM1 (MFMA): z1 = nf @ W1 ----
    {
        f16x8 bf[4][2];
#pragma unroll
        for (int ks = 0; ks < 4; ks++)
#pragma unroll
            for (int nt = 0; nt < 2; nt++) {
                int nb = wave * 2 + nt;
                bf[ks][nt] = *(const f16x8*)&wnp[(((ks * 8 + nb) * 64 + lane) << 3)];
            }
#pragma unroll
        for (int mt = 0; mt < 4; mt++)
#pragma unroll
            for (int nt = 0; nt < 2; nt++) acc[mt][nt] = (f32x4){0.f, 0.f, 0.f, 0.f};
#pragma unroll
        for (int ks = 0; ks < 4; ks++) {
#pragma unroll
            for (int mt = 0; mt < 4; mt++) {
                f16x8 af = *(const f16x8*)&Ah[(mt * 16 + lrow) * 136 + ks * 32 + lgrp * 8];
                acc[mt][0] = __builtin_amdgcn_mfma_f32_16x16x32_f16(af, bf[ks][0], acc[mt][0], 0, 0, 0);
                acc[mt][1] = __builtin_amdgcn_mfma_f32_16x16x32_f16(af, bf[ks][1], acc[mt][1], 0, 0, 0);
            }
        }
    }
    __syncthreads();   // all GEMM1 A-reads done

    // epilogue1: z1 = silu(acc + tgW[batch[n]][col]) -> Ah row-major
#pragma unroll
    for (int mt = 0; mt < 4; mt++) {
#pragma unroll
        for (int nt = 0; nt < 2; nt++) {
            int col = wave * 32 + nt * 16 + lrow;
#pragma unroll
            for (int reg = 0; reg < 4; reg++) {
                int row = mt * 16 + lgrp * 4 + reg;
                int n = rowBase + row;
                float v = acc[mt][nt][reg];
                if (n < Nrows) v += tgW[(size_t)batch[n] * H + col];
                Ah[row * 136 + col] = __float2half(silu_f(v));
            }
        }
    }
    __syncthreads();

    // ---- GEMM2 (MFMA): z2 = z1 @ W2 ----
    {
        const __half* w2 = wnp + 16384;
        f16x8 bf[4][2];
#pragma unroll
        for (int ks = 0; ks < 4; ks++)
#pragma unroll
            for (int nt = 0; nt < 2; nt++) {
                int nb = wave * 2 + nt;
                bf[ks][nt] = *(const f16x8*)&w2[(((ks * 8 + nb) * 64 + lane) << 3)];
            }
#pragma unroll
        for (int mt = 0; mt < 4; mt++)
#pragma unroll
            for (int nt = 0; nt < 2; nt++) acc[mt][nt] = (f32x4){0.f, 0.f, 0.f, 0.f};
#pragma unroll
        for (int ks = 0; ks < 4; ks++) {
#pragma unroll
            for (int mt = 0; mt < 4; mt++) {
                f16x8 af = *(const f16x8*)&Ah[(mt * 16 + lrow) * 136 + ks * 32 + lgrp * 8];
                acc[mt][0] = __builtin_amdgcn_mfma_f32_16x16x32_f16(af, bf[ks][0], acc[mt][0], 0, 0, 0);
                acc[mt][1] = __builtin_amdgcn_mfma_f32_16x16x32_f16(af, bf[ks][1], acc[mt][1], 0, 0, 0);
            }
        }
    }
    __syncthreads();   // all GEMM2 A-reads done before overwrite

    // epilogue2: z2 = silu(acc + b2) -> Ah row-major (reuse)
#pragma unroll
    for (int mt = 0; mt < 4; mt++) {
#pragma unroll
        for (int nt = 0; nt < 2; nt++) {
            int col = wave * 32 + nt * 16 + lrow;
            float b2 = npb2[col];
#pragma unroll
            for (int reg = 0; reg < 4; reg++) {
                int row = mt * 16 + lgrp * 4 + reg;
                Ah[row * 136 + col] = __float2half(silu_f(acc[mt][nt][reg] + b2));
            }
        }
    }
    __syncthreads();

    // ---- GEMM3 (MFMA): out[64,48-pad] = z2 @ W3pad; wave owns 16 rows x 48 cols
    {
        const __half* w3 = wnp + 32768;
        f32x4 acc3[3];
#pragma unroll
        for (int nt = 0; nt < 3; nt++) acc3[nt] = (f32x4){0.f, 0.f, 0.f, 0.f};
#pragma unroll
        for (int ks = 0; ks < 4; ks++) {
            f16x8 af = *(const f16x8*)&Ah[(wave * 16 + lrow) * 136 + ks * 32 + lgrp * 8];
#pragma unroll
            for (int nt = 0; nt < 3; nt++) {
                f16x8 bf = *(const f16x8*)&w3[(((ks * 3 + nt) * 64 + lane) << 3)];
                acc3[nt] = __builtin_amdgcn_mfma_f32_16x16x32_f16(af, bf, acc3[nt], 0, 0, 0);
            }
        }
#pragma unroll
        for (int nt = 0; nt < 3; nt++) {
            int col = nt * 16 + lrow;
            if (col < AD) {
                float b3 = npb3[col];
#pragma unroll
                for (int reg = 0; reg < 4; reg++) {
                    int row = rowBase + wave * 16 + lgrp * 4 + reg;
                    if (row < Nrows) out[(size_t)row * AD + col] = acc3[nt][reg] + b3;
                }
            }
        }
    }
}

// ---------------------------------------------------------------------------
// CSR build
// ---------------------------------------------------------------------------
__global__ __launch_bounds__(256) void hist_dst(const int* __restrict__ edge_index,
                                                int* __restrict__ deg)
{
    int e = blockIdx.x * 256 + threadIdx.x;
    if (e < N_EDGES) atomicAdd(&deg[edge_index[N_EDGES + e]], 1);
}

__global__ __launch_bounds__(256) void scan_part(const int* __restrict__ cnt,
                                                 int* __restrict__ bsum, int n)
{
    int tid = threadIdx.x;
    int i0 = blockIdx.x * 1024 + tid * 4;
    int s = 0;
#pragma unroll
    for (int j = 0; j < 4; j++) if (i0 + j < n) s += cnt[i0 + j];
    __shared__ int red[256];
    red[tid] = s;
    __syncthreads();
    for (int off = 128; off >= 1; off >>= 1) {
        if (tid < off) red[tid] += red[tid + off];
        __syncthreads();
    }
    if (tid == 0) bsum[blockIdx.x] = red[0];
}

__global__ __launch_bounds__(256) void scan_tops(const int* __restrict__ bsum,
                                                 int* __restrict__ boff, int G,
                                                 int* __restrict__ total)
{
    int tid = threadIdx.x;
    int v = (tid < G) ? bsum[tid] : 0;
    __shared__ int ps[256];
    ps[tid] = v;
    __syncthreads();
    for (int off = 1; off < 256; off <<= 1) {
        int t = (tid >= off) ? ps[tid - off] : 0;
        __syncthreads();
        ps[tid] += t;
        __syncthreads();
    }
    if (tid < G) boff[tid] = ps[tid] - v;
    if (tid == 255) *total = ps[255];
}

// scan_final also emits gcur[b] = csr_ptr[b*256] (bucket base cursors).
__global__ __launch_bounds__(256) void scan_final(const int* __restrict__ cnt,
                                                  const int* __restrict__ boff,
                                                  int* __restrict__ ptr,
                                                  int* __restrict__ gcur, int n)
{
    int tid = threadIdx.x;
    int i0 = blockIdx.x * 1024 + tid * 4;
    int v[4];
#pragma unroll
    for (int j = 0; j < 4; j++) v[j] = (i0 + j < n) ? cnt[i0 + j] : 0;
    int s = v[0] + v[1] + v[2] + v[3];
    __shared__ int ps[256];
    ps[tid] = s;
    __syncthreads();
    for (int off = 1; off < 256; off <<= 1) {
        int t = (tid >= off) ? ps[tid - off] : 0;
        __syncthreads();
        ps[tid] += t;
        __syncthreads();
    }
    int run = boff[blockIdx.x] + ps[tid] - s;
    if ((i0 & 255) == 0 && (i0 >> 8) < NBUCK && i0 < n) gcur[i0 >> 8] = run;
#pragma unroll
    for (int j = 0; j < 4; j++) {
        if (i0 + j < n) { ptr[i0 + j] = run; run += v[j]; }
    }
}

// ---------------------------------------------------------------------------
// Bucketed scatter pass A
// ---------------------------------------------------------------------------
__global__ __launch_bounds__(256) void bucket_scatter_a(
    const int* __restrict__ edge_index, int* __restrict__ gcur,
    int4* __restrict__ tmp)
{
    __shared__ int cnt[NBUCK], cbase[NBUCK], cur[NBUCK];
    const int tid = threadIdx.x;
    const int e0 = blockIdx.x * EPB;
    for (int i = tid; i < NBUCK; i += 256) { cnt[i] = 0; cur[i] = 0; }
    __syncthreads();
    for (int i = 0; i < EPB; i += 256) {
        int e = e0 + i + tid;
        if (e < N_EDGES) atomicAdd(&cnt[edge_index[N_EDGES + e] >> 8], 1);
    }
    __syncthreads();
    for (int i = tid; i < NBUCK; i += 256)
        if (cnt[i] > 0) cbase[i] = atomicAdd(&gcur[i], cnt[i]);
    __syncthreads();
    for (int i = 0; i < EPB; i += 256) {
        int e = e0 + i + tid;
        if (e < N_EDGES) {
            int s = edge_index[e];
            int d = edge_index[N_EDGES + e];
            int b = d >> 8;
            int off = atomicAdd(&cur[b], 1);
            tmp[cbase[b] + off] = make_int4(s, e, d, 0);
        }
    }
}

// Pass B: block = bucket; LDS per-node cursors; local scatter to csr_se.
__global__ __launch_bounds__(256) void bucket_scatter_b(
    const int4* __restrict__ tmp, const int* __restrict__ csr_ptr,
    int2* __restrict__ csr_se)
{
    __shared__ int lcur[256];
    const int b = blockIdx.x;
    const int n0 = b << 8;
    const int tid = threadIdx.x;
    lcur[tid] = 0;
    __syncthreads();
    int start = csr_ptr[n0];
    int end   = csr_ptr[min(n0 + 256, N_NODES)];
    for (int p = start + tid; p < end; p += 256) {
        int4 q = tmp[p];
        int pos = atomicAdd(&lcur[q.z - n0], 1);
        csr_se[csr_ptr[q.z] + pos] = make_int2(q.x, q.y);
    }
}

// ---------------------------------------------------------------------------
// se3[l][p][hh] = edge_attr[e(p)] @ M_l[:,hh] + c_l[hh]  (all 3 layers, once)
// ---------------------------------------------------------------------------
__global__ __launch_bounds__(256) void se3_pre(
    const int2* __restrict__ csr_se, const float* __restrict__ edge_attr,
    const float* __restrict__ mc, __half* __restrict__ se3)
{
    __shared__ float Ml[LAYERS * 44];
    int tid = threadIdx.x;
    if (tid < LAYERS * 44) Ml[tid] = mc[tid];
    __syncthreads();
    int p = blockIdx.x * 256 + tid;
    if (p >= N_EDGES) return;
    int e = csr_se[p].y;
    float ea[BD];
    const float* eap = &edge_attr[(size_t)e * BD];
#pragma unroll
    for (int j = 0; j < BD; j++) ea[j] = eap[j];
#pragma unroll
    for (int l = 0; l < LAYERS; l++) {
        const float* M = &Ml[l * 44];
        float s0 = M[40], s1 = M[41], s2 = M[42], s3 = M[43];
#pragma unroll
        for (int j = 0; j < BD; j++) {
            float x = ea[j];
            s0 += x * M[j * 4 + 0]; s1 += x * M[j * 4 + 1];
            s2 += x * M[j * 4 + 2]; s3 += x * M[j * 4 + 3];
        }
        __half2 h01 = __floats2half2_rn(s0, s1);
        __half2 h23 = __floats2half2_rn(s2, s3);
        uint2 u = make_uint2(*(const unsigned*)&h01, *(const unsigned*)&h23);
        *(uint2*)&se3[((size_t)l * N_EDGES + p) * 4] = u;
    }
}

// ---------------------------------------------------------------------------
// GAT aggregation (r22 v1 structure, no-max softmax).
// ---------------------------------------------------------------------------
__global__ __launch_bounds__(256) void gat_agg_full(
    const __half* __restrict__ xh16, const __half* __restrict__ se3l,
    const float* __restrict__ sS,
    const int* __restrict__ csr_ptr, const int2* __restrict__ csr_se,
    const float* __restrict__ sD, const float* __restrict__ conv_b_l,
    __half* __restrict__ agg)
{
    int n = (blockIdx.x * 256 + threadIdx.x) >> 6;
    if (n >= N_NODES) return;
    int lane = threadIdx.x & 63;
    int c0 = lane * 2;
    int hd = lane >> 4;
    int start = csr_ptr[n], end = csr_ptr[n + 1];
    float sDn = sD[n * 4 + hd];

    float d_run = 0.f;
    float acc0 = 0.f, acc1 = 0.f;

    for (int base = start; base < end; base += 64) {
        int cnt = min(64, end - base);
        int s_l = (lane < cnt) ? (csr_se[base + lane].x << 7) : 0;

        float e_t[4];
        float dsum = 0.f;
#pragma unroll
        for (int t = 0; t < 4; t++) {
            int i = (lane & 15) + t * 16;
            float e = 0.f;
            if (i < cnt) {
                int src7 = __shfl(s_l, i);
                float a = sS[(src7 >> 5) + hd] +
                    __half2float(se3l[(size_t)(base + i) * 4 + hd]) + sDn;
                a = (a >= 0.f) ? a : 0.2f * a;
                e = __expf(a);
            }
            e_t[t] = e;
            dsum += e;
        }
#pragma unroll
        for (int off = 8; off >= 1; off >>= 1)
            dsum += __shfl_xor(dsum, off, 16);
        d_run += dsum;

        int srcb = lane & 48;
#pragma unroll
        for (int t = 0; t < 4; t++) {
            int rem = cnt - t * 16;
            if (rem <= 0) break;
            int lim = min(16, (rem + 3) & ~3);
            for (int i2 = 0; i2 < lim; i2 += 4) {
                int i = t * 16 + i2;
                int s0 = __shfl(s_l, i + 0), s1 = __shfl(s_l, i + 1);
                int s2 = __shfl(s_l, i + 2), s3 = __shfl(s_l, i + 3);
                float w0 = __shfl(e_t[t], srcb | (i2 + 0));
                float w1 = __shfl(e_t[t], srcb | (i2 + 1));
                float w2 = __shfl(e_t[t], srcb | (i2 + 2));
                float w3 = __shfl(e_t[t], srcb | (i2 + 3));
                float2 x0 = __half22float2(*(const __half2*)&xh16[s0 + c0]);
                float2 x1 = __half22float2(*(const __half2*)&xh16[s1 + c0]);
                float2 x2 = __half22float2(*(const __half2*)&xh16[s2 + c0]);
                float2 x3 = __half22float2(*(const __half2*)&xh16[s3 + c0]);
                acc0 += x0.x * w0 + x1.x * w1 + x2.x * w2 + x3.x * w3;
                acc1 += x0.y * w0 + x1.y * w1 + x2.y * w2 + x3.y * w3;
            }
        }
    }
    float inv = 1.f / (d_run + 1e-16f);
    __half2 o = __floats2half2_rn(acc0 * inv + conv_b_l[c0],
                                  acc1 * inv + conv_b_l[c0 + 1]);
    *(__half2*)&agg[(size_t)n * H + c0] = o;
}

// ---------------------------------------------------------------------------
// BatchNorm stats, fused partial+finish (last-block-done pattern).
// 512 blocks; block writes its partials, then the last to finish reduces
// all partials and emits scale/shift.
// ---------------------------------------------------------------------------
__global__ __launch_bounds__(256) void bn_stats(
    const __half* __restrict__ agg, float* __restrict__ part,
    const float* __restrict__ gamma, const float* __restrict__ beta,
    float* __restrict__ scale, float* __restrict__ shift,
    int* __restrict__ counter)
{
    const int PER = (N_NODES + 511) / 512;   // 98
    __shared__ float red[2][8][128];
    int b = blockIdx.x;
    int tid = threadIdx.x;
    int cg = tid & 31;
    int rs = tid >> 5;   // 0..7
    int c4 = cg * 4;
    int s = b * PER, e = min(N_NODES, s + PER);
    float s0 = 0.f, s1 = 0.f, s2 = 0.f, s3 = 0.f;
    float q0 = 0.f, q1 = 0.f, q2 = 0.f, q3 = 0.f;
    for (int n = s + rs; n < e; n += 8) {
        uint2 u = *(const uint2*)&agg[(size_t)n * H + c4];
        float2 lo = __half22float2(*(__half2*)&u.x);
        float2 hi = __half22float2(*(__half2*)&u.y);
        s0 += lo.x; q0 += lo.x * lo.x;
        s1 += lo.y; q1 += lo.y * lo.y;
        s2 += hi.x; q2 += hi.x * hi.x;
        s3 += hi.y; q3 += hi.y * hi.y;
    }
    *(float4*)&red[0][rs][c4] = make_float4(s0, s1, s2, s3);
    *(float4*)&red[1][rs][c4] = make_float4(q0, q1, q2, q3);
    __syncthreads();
    if (tid < 128) {
        int c = tid;
        float sum = 0.f, sq = 0.f;
#pragma unroll
        for (int r = 0; r < 8; r++) { sum += red[0][r][c]; sq += red[1][r][c]; }
        part[b * H + c] = sum;
        part[512 * H + b * H + c] = sq;
    }
    // last-block-done: finish reduction
    __shared__ int isLast;
    __threadfence();
    __syncthreads();
    if (tid == 0) isLast = (atomicAdd(counter, 1) == 511) ? 1 : 0;
    __syncthreads();
    if (!isLast) return;
    __threadfence();
    __shared__ double redd[2][2][128];
    int c = tid & 127;
    int g = tid >> 7;
    double ds = 0.0, dq = 0.0;
    for (int bb = g * 256; bb < (g + 1) * 256; bb++) {
        ds += (double)part[bb * H + c];
        dq += (double)part[512 * H + bb * H + c];
    }
    redd[0][g][c] = ds;
    redd[1][g][c] = dq;
    __syncthreads();
    if (g == 0) {
        ds = redd[0][0][c] + redd[0][1][c];
        dq = redd[1][0][c] + redd[1][1][c];
        float mu = (float)(ds / N_NODES);
        float var = (float)(dq / N_NODES) - mu * mu;
        float rstd = rsqrtf(var + 1e-5f);
        float sc = gamma[c] * rstd;
        scale[c] = sc;
        shift[c] = beta[c] - mu * sc;
    }
}

// ---------------------------------------------------------------------------
// Graph head MLP with fused mean-pool (block g, 4 thread-quarters).
// ---------------------------------------------------------------------------
__global__ __launch_bounds__(512) void graph_head_mlp(
    const int* __restrict__ gptr, const float* __restrict__ nf,
    const float* __restrict__ t_emb,
    const float* __restrict__ pW1, const float* __restrict__ pb1,
    const float* __restrict__ pW2, const float* __restrict__ pb2,
    const float* __restrict__ npW1, const float* __restrict__ npb1,
    float* __restrict__ tgW)
{
    int g = blockIdx.x;
    int c = threadIdx.x & 127;
    int q = threadIdx.x >> 7;
    __shared__ float row[H], z[H];
    __shared__ float red[4][H];

    int s = gptr[g], e = gptr[g + 1];
    float cf = (e - s > 0) ? (float)(e - s) : 1.f;
    int qlen = (e - s + 3) >> 2;
    int qs = s + q * qlen;
    int qe = min(e, qs + qlen);
    float sum = 0.f;
    for (int n = qs; n < qe; n++) sum += nf[(size_t)n * H + c];
    red[q][c] = sum;
    __syncthreads();
    if (q == 0) row[c] = (red[0][c] + red[1][c] + red[2][c] + red[3][c]) / cf;
    __syncthreads();

    float p = 0.f;
#pragma unroll 8
    for (int k = q * 32; k < q * 32 + 32; k++) p += row[k] * pW1[k * H + c];
    red[q][c] = p;
    __syncthreads();
    if (q == 0) z[c] = silu_f(red[0][c] + red[1][c] + red[2][c] + red[3][c] + pb1[c]);
    __syncthreads();

    p = 0.f;
#pragma unroll 8
    for (int k = q * 32; k < q * 32 + 32; k++) p += z[k] * pW2[k * H + c];
    red[q][c] = p;
    __syncthreads();
    if (q == 0) row[c] = red[0][c] + red[1][c] + red[2][c] + red[3][c] + pb2[c]
                         + t_emb[g * H + c];
    __syncthreads();

    p = 0.f;
#pragma unroll 8
    for (int k = q * 32; k < q * 32 + 32; k++)
        p += row[k] * npW1[(size_t)(128 + k) * H + c];
    red[q][c] = p;
    __syncthreads();
    if (q == 0) tgW[g * H + c] = red[0][c] + red[1][c] + red[2][c] + red[3][c] + npb1[c];
}

// ---------------------------------------------------------------------------
extern "C" void kernel_launch(void* const* d_in, const int* in_sizes, int n_in,
                              void* d_out, int out_size, void* d_ws, size_t ws_size,
                              hipStream_t stream)
{
    const float* x          = (const float*)d_in[0];
    const int*   edge_index = (const int*)d_in[1];
    const float* edge_attr  = (const float*)d_in[2];
    const int*   batch      = (const int*)d_in[3];
    const int*   t          = (const int*)d_in[4];
    const float* atom_W     = (const float*)d_in[5];
    const float* atom_b     = (const float*)d_in[6];
    const float* bond_W     = (const float*)d_in[7];
    const float* bond_b     = (const float*)d_in[8];
    const float* lin_W      = (const float*)d_in[9];
    const float* edge_W     = (const float*)d_in[10];
    const float* att_src    = (const float*)d_in[11];
    const float* att_dst    = (const float*)d_in[12];
    const float* att_edge   = (const float*)d_in[13];
    const float* conv_b     = (const float*)d_in[14];
    const float* bn_gamma   = (const float*)d_in[15];
    const float* bn_beta    = (const float*)d_in[16];
    const float* out_W      = (const float*)d_in[17];
    const float* out_b      = (const float*)d_in[18];
    const float* time_W1    = (const float*)d_in[19];
    const float* time_b1    = (const float*)d_in[20];
    const float* time_W2    = (const float*)d_in[21];
    const float* time_b2    = (const float*)d_in[22];
    const float* pool_W1    = (const float*)d_in[23];
    const float* pool_b1    = (const float*)d_in[24];
    const float* pool_W2    = (const float*)d_in[25];
    const float* pool_b2    = (const float*)d_in[26];
    const float* np_W1      = (const float*)d_in[27];
    const float* np_b1      = (const float*)d_in[28];
    const float* np_W2      = (const float*)d_in[29];
    const float* np_b2      = (const float*)d_in[30];
    const float* np_W3      = (const float*)d_in[31];
    const float* np_b3      = (const float*)d_in[32];

    // ---------------- workspace layout (floats) ----------------
    const size_t OFF_H     = 0;
    const size_t OFF_XH    = 6400000;
    const size_t OFF_AGG   = 12800000;
    const size_t OFF_SD    = 17600000;
    const size_t OFF_TEMB  = 17800000;
    const size_t OFF_TGW   = 17832768;
    const size_t OFF_MC    = 17865536;
    const size_t OFF_BNSC  = 17865792;
    const size_t OFF_BNSH  = 17865920;
    const size_t OFF_PART  = 17866048;
    const size_t OFF_SE3   = 17898816;               // half[3][E][4]
    const size_t REQ_FLOATS = 22698816;
    const size_t REQ_BYTES  = REQ_FLOATS * 4;        // 90.8 MB

    if (ws_size < REQ_BYTES) {
        hipMemsetAsync(d_out, 0, (size_t)out_size * sizeof(float), stream);
        return;
    }

    float* fws    = (float*)d_ws;
    float* h      = fws + OFF_H;
    float* xh     = fws + OFF_XH;
    __half* xh16  = (__half*)(fws + OFF_XH);
    int4*  etmp   = (int4*)(fws + OFF_XH);
    __half* agg   = (__half*)(fws + OFF_AGG);
    float* sD     = fws + OFF_SD;
    float* t_emb  = fws + OFF_TEMB;
    float* tgW    = fws + OFF_TGW;
    float* mc     = fws + OFF_MC;
    float* bnsc   = fws + OFF_BNSC;
    float* bnsh   = fws + OFF_BNSH;
    float* part   = fws + OFF_PART;
    __half* wnp   = (__half*)part;
    __half* se3   = (__half*)(fws + OFF_SE3);

    int* ib       = (int*)d_out;
    int* csr_ptr  = ib;
    int2* csr_se  = (int2*)(ib + 50016);
    int* deg      = ib + 1650016;          // 50016 ints memset; [50000..50002] = bn counters
    int* bncnt    = deg + 50000;
    int* gptr     = ib + 1700032;
    int* bsum     = ib + 1700292;
    int* boff     = ib + 1700356;
    float* sS     = (float*)d_out + 1700420;
    float* bnpart = sS;
    __half* w16   = (__half*)((float*)d_out + 1900420);  // 65536 halves -> ends 1933188
    int* gcur     = ib + 1933188;                        // 196 ints (no aliasing)

    hipMemsetAsync(deg, 0, 50016 * sizeof(int), stream);

    // merged setup (blocks 0..257) + weight packing (blocks 258..665)
    setup_all<<<NB + 2 + (4 * H * H + 2 * H * H + H * 48 + 255) / 256, 256, 0, stream>>>(
        edge_W, att_edge, bond_W, bond_b, mc,
        batch, gptr, t, time_W1, time_b1, time_W2, time_b2, t_emb,
        lin_W, out_W, np_W1, np_W2, np_W3, w16, wnp);

    hist_dst<<<(N_EDGES + 255) / 256, 256, 0, stream>>>(edge_index, deg);

    const int GSN = (N_NODES + 1023) / 1024;
    scan_part<<<GSN, 256, 0, stream>>>(deg, bsum, N_NODES);
    scan_tops<<<1, 256, 0, stream>>>(bsum, boff, GSN, &csr_ptr[N_NODES]);
    scan_final<<<GSN, 256, 0, stream>>>(deg, boff, csr_ptr, gcur, N_NODES);

    bucket_scatter_a<<<(N_EDGES + EPB - 1) / EPB, 256, 0, stream>>>(
        edge_index, gcur, etmp);
    bucket_scatter_b<<<NBUCK, 256, 0, stream>>>(etmp, csr_ptr, csr_se);

    const int GB = (N_NODES + 63) / 64;
    const int GE = (N_EDGES + 255) / 256;

    se3_pre<<<GE, 256, 0, stream>>>(csr_se, edge_attr, mc, se3);

    gemm128<AD><<<GB, 256, 0, stream>>>(x, atom_W, atom_b, h, N_NODES, H);

    for (int l = 0; l < LAYERS; l++) {
        gemm_mfma_bn<<<GB, 256, 0, stream>>>(
            (l == 0) ? h : nullptr,
            (l == 0) ? nullptr : agg, bnsc, bnsh, h,
            w16 + (size_t)l * 16384, nullptr,
            nullptr, xh16,
            att_src + l * H, att_dst + l * H, sS, sD, N_NODES);
        gat_agg_full<<<N_NODES / 4, 256, 0, stream>>>(
            xh16, se3 + (size_t)l * N_EDGES * 4, sS,
            csr_ptr, csr_se, sD, conv_b + l * H, agg);
        bn_stats<<<512, 256, 0, stream>>>(agg, bnpart, bn_gamma + l * H,
                                          bn_beta + l * H, bnsc, bnsh, bncnt + l);
    }

    gemm_mfma_bn<<<GB, 256, 0, stream>>>(
        nullptr, agg, bnsc, bnsh, h,
        w16 + (size_t)3 * 16384, out_b,
        xh, nullptr,
        nullptr, nullptr, nullptr, nullptr, N_NODES);

    graph_head_mlp<<<NB, 512, 0, stream>>>(gptr, xh, t_emb, pool_W1, pool_b1,
                                           pool_W2, pool_b2, np_W1, np_b1, tgW);

    np_fused_mfma<<<GB, 256, 0, stream>>>(xh, batch, tgW, wnp, np_b2, np_b3,
                                          (float*)d_out, N_NODES);
}

// Round 28
// 419.194 us; speedup vs baseline: 1.2701x; 1.2701x over previous
//
#include <hip/hip_runtime.h>
#include <hip/hip_fp16.h>
#include <math.h>

#define N_NODES 50000
#define N_EDGES 800000
#define NB 256
#define AD 39
#define BD 10
#define H 128
#define HEADS 4
#define HD 32
#define LAYERS 3
#define TD 128
#define NBUCK 196
#define EPB 4096

typedef _Float16 f16x8 __attribute__((ext_vector_type(8)));
typedef float f32x4 __attribute__((ext_vector_type(4)));

__device__ __forceinline__ float silu_f(float x) { return x / (1.f + __expf(-x)); }

// ---------------------------------------------------------------------------
// Generic vector GEMM (only used for the atom embedding, K=39)
// ---------------------------------------------------------------------------
__device__ __forceinline__ void fma_rank1(float acc[8][4], float4 aL, float4 aH, float4 w)
{
    float ar[8] = {aL.x, aL.y, aL.z, aL.w, aH.x, aH.y, aH.z, aH.w};
    float wr[4] = {w.x, w.y, w.z, w.w};
#pragma unroll
    for (int r = 0; r < 8; r++)
#pragma unroll
        for (int j = 0; j < 4; j++) acc[r][j] += ar[r] * wr[j];
}

template<int KT>
__global__ __launch_bounds__(256) void gemm128(
    const float* __restrict__ A, const float* __restrict__ W,
    const float* __restrict__ bias, float* __restrict__ out,
    int Nrows, int ldw)
{
    __shared__ float As[KT * 68];
    const int tid = threadIdx.x;
    const int rowBase = blockIdx.x * 64;

    for (int idx = tid; idx < 64 * KT; idx += 256) {
        int row = idx / KT;
        int k = idx - row * KT;
        int n = rowBase + row;
        As[k * 68 + row] = (n < Nrows) ? A[(size_t)n * KT + k] : 0.f;
    }
    __syncthreads();

    const int c0 = (tid & 31) * 4;
    const int n0 = (tid >> 5) * 8;

    float acc[8][4];
#pragma unroll
    for (int r = 0; r < 8; r++)
#pragma unroll
        for (int j = 0; j < 4; j++) acc[r][j] = 0.f;

    const float* wp = W + c0;
    int k = 0;
    for (; k + 4 <= KT; k += 4) {
        float4 w0 = *(const float4*)&wp[(size_t)(k + 0) * ldw];
        float4 w1 = *(const float4*)&wp[(size_t)(k + 1) * ldw];
        float4 w2 = *(const float4*)&wp[(size_t)(k + 2) * ldw];
        float4 w3 = *(const float4*)&wp[(size_t)(k + 3) * ldw];
        float4 aL0 = *(const float4*)&As[(k + 0) * 68 + n0];
        float4 aH0 = *(const float4*)&As[(k + 0) * 68 + n0 + 4];
        float4 aL1 = *(const float4*)&As[(k + 1) * 68 + n0];
        float4 aH1 = *(const float4*)&As[(k + 1) * 68 + n0 + 4];
        float4 aL2 = *(const float4*)&As[(k + 2) * 68 + n0];
        float4 aH2 = *(const float4*)&As[(k + 2) * 68 + n0 + 4];
        float4 aL3 = *(const float4*)&As[(k + 3) * 68 + n0];
        float4 aH3 = *(const float4*)&As[(k + 3) * 68 + n0 + 4];
        fma_rank1(acc, aL0, aH0, w0);
        fma_rank1(acc, aL1, aH1, w1);
        fma_rank1(acc, aL2, aH2, w2);
        fma_rank1(acc, aL3, aH3, w3);
    }
    for (; k < KT; ++k) {
        float4 w0 = *(const float4*)&wp[(size_t)k * ldw];
        float4 aL = *(const float4*)&As[k * 68 + n0];
        float4 aH = *(const float4*)&As[k * 68 + n0 + 4];
        fma_rank1(acc, aL, aH, w0);
    }

    float4 bv = make_float4(0.f, 0.f, 0.f, 0.f);
    if (bias) bv = *(const float4*)&bias[c0];

#pragma unroll
    for (int r = 0; r < 8; r++) {
        int n = rowBase + n0 + r;
        if (n >= Nrows) break;
        float4 o;
        o.x = acc[r][0] + bv.x;
        o.y = acc[r][1] + bv.y;
        o.z = acc[r][2] + bv.z;
        o.w = acc[r][3] + bv.w;
        *(float4*)&out[(size_t)n * H + c0] = o;
    }
}

// ---------------------------------------------------------------------------
// Merged setup + weight packing:
//   block 0       : edge-path fold (mc)
//   block 1       : gptr bsearch
//   blocks 2..257 : time embedding
//   blocks 258+   : w16 (lin_W x3 + out_W) and np W1/W2/W3pad fragments
// ---------------------------------------------------------------------------
__global__ __launch_bounds__(256) void setup_all(
    const float* __restrict__ edge_W, const float* __restrict__ att_edge,
    const float* __restrict__ bond_W, const float* __restrict__ bond_b,
    float* __restrict__ mc,
    const int* __restrict__ batch, int* __restrict__ gptr,
    const int* __restrict__ t,
    const float* __restrict__ W1, const float* __restrict__ b1,
    const float* __restrict__ W2, const float* __restrict__ b2,
    float* __restrict__ t_emb,
    const float* __restrict__ lin_W, const float* __restrict__ out_W,
    const float* __restrict__ npW1, const float* __restrict__ npW2,
    const float* __restrict__ npW3,
    __half* __restrict__ w16, __half* __restrict__ wnp)
{
    const int b = blockIdx.x;
    const int tid = threadIdx.x;
    if (b == 0) {
        __shared__ float bl[LAYERS][H][4];
        for (int task = tid; task < LAYERS * H; task += 256) {
            int l = task / H, k = task % H;
#pragma unroll
            for (int hh = 0; hh < 4; hh++) {
                float s = 0.f;
                for (int d = 0; d < HD; d++)
                    s += edge_W[(size_t)l * H * H + k * H + hh * HD + d] *
                         att_edge[l * H + hh * HD + d];
                bl[l][k][hh] = s;
            }
        }
        __syncthreads();
        if (tid < LAYERS * BD * 4) {
            int l = tid / (BD * 4), r = tid % (BD * 4), j = r / 4, hh = r % 4;
            float s = 0.f;
            for (int k = 0; k < H; k++) s += bond_W[j * H + k] * bl[l][k][hh];
            mc[l * 44 + j * 4 + hh] = s;
        }
        if (tid >= 128 && tid < 128 + LAYERS * 4) {
            int r = tid - 128, l = r / 4, hh = r % 4;
            float s = 0.f;
            for (int k = 0; k < H; k++) s += bond_b[k] * bl[l][k][hh];
            mc[l * 44 + 40 + hh] = s;
        }
    } else if (b == 1) {
        for (int g = tid; g <= NB; g += 256) {
            int lo = 0, hi = N_NODES;
            while (lo < hi) {
                int mid = (lo + hi) >> 1;
                if (batch[mid] < g) lo = mid + 1; else hi = mid;
            }
            gptr[g] = lo;
        }
    } else if (b < NB + 2) {
        int g = b - 2;
        int c = tid & 127;
        float tf = (float)t[g];
        __shared__ float emb[TD], z[H];
        int k = c & 63;
        float f = __expf(-9.210340371976184f * (float)k / 63.0f);
        float e = tf * f;
        emb[c] = (c < 64) ? sinf(e) : cosf(e);
        __syncthreads();
        float a1 = b1[c];
        for (int kk = 0; kk < TD; kk++) a1 += emb[kk] * W1[kk * H + c];
        z[c] = silu_f(a1);
        __syncthreads();
        float a2 = b2[c];
        for (int kk = 0; kk < H; kk++) a2 += z[kk] * W2[kk * H + c];
        t_emb[g * H + c] = a2;
    } else {
        int idx = (b - (NB + 2)) * 256 + tid;
        if (idx < 4 * H * H) {
            int mat = idx >> 14;
            int rem = idx & 16383;
            int k = rem >> 7;
            int n = rem & 127;
            const float* src = (mat < 3) ? (lin_W + (size_t)mat * H * H) : out_W;
            float v = src[(size_t)k * H + n];
            int ks = k >> 5, kr = k & 31;
            int lane = ((kr >> 3) << 4) | (n & 15);
            int j = kr & 7;
            int nb = n >> 4;
            w16[(size_t)mat * 16384 + (((ks * 8 + nb) * 64 + lane) << 3) + j] = __float2half(v);
            return;
        }
        int r = idx - 4 * H * H;
        if (r < 2 * H * H) {
            int mat = r >> 14;
            int rem = r & 16383;
            int k = rem >> 7;
            int n = rem & 127;
            const float* src = mat ? npW2 : npW1;
            float v = src[(size_t)k * H + n];
            int ks = k >> 5, kr = k & 31;
            int lane = ((kr >> 3) << 4) | (n & 15);
            int j = kr & 7;
            int nb = n >> 4;
            wnp[(size_t)mat * 16384 + (((ks * 8 + nb) * 64 + lane) << 3) + j] = __float2half(v);
            return;
        }
        r -= 2 * H * H;
        if (r >= H * 48) return;
        int k = r / 48;
        int n = r - k * 48;
        float v = (n < AD) ? npW3[(size_t)k * AD + n] : 0.f;
        int ks = k >> 5, kr = k & 31;
        int lane = ((kr >> 3) << 4) | (n & 15);
        int j = kr & 7;
        int nb = n >> 4;
        wnp[32768 + (((ks * 3 + nb) * 64 + lane) << 3) + j] = __float2half(v);
    }
}

// ---------------------------------------------------------------------------
// MFMA GEMM with fused BN-apply staging and fused attention-score epilogue.
// ---------------------------------------------------------------------------
__global__ __launch_bounds__(256) void gemm_mfma_bn(
    const float* __restrict__ A,
    const __half* __restrict__ agg, const float* __restrict__ scale,
    const float* __restrict__ shift, float* __restrict__ hio,
    const __half* __restrict__ wfrag, const float* __restrict__ bias,
    float* __restrict__ out32, __half* __restrict__ out16,
    const float* __restrict__ attS, const float* __restrict__ attD,
    float* __restrict__ sS, float* __restrict__ sD, int Nrows)
{
    __shared__ __half Ah[64 * 136];
    const int tid = threadIdx.x;
    const int rowBase = blockIdx.x * 64;

    for (int idx = tid; idx < 64 * 32; idx += 256) {
        int row = idx >> 5;
        int kq = (idx & 31) * 4;
        int n = rowBase + row;
        float4 v = make_float4(0.f, 0.f, 0.f, 0.f);
        if (n < Nrows) {
            if (agg) {
                uint2 u = *(const uint2*)&agg[(size_t)n * H + kq];
                float2 lo = __half22float2(*(__half2*)&u.x);
                float2 hi = __half22float2(*(__half2*)&u.y);
                float4 sc = *(const float4*)&scale[kq];
                float4 sh = *(const float4*)&shift[kq];
                float4 hv = *(const float4*)&hio[(size_t)n * H + kq];
                v.x = fmaxf(lo.x * sc.x + sh.x, 0.f) + hv.x;
                v.y = fmaxf(lo.y * sc.y + sh.y, 0.f) + hv.y;
                v.z = fmaxf(hi.x * sc.z + sh.z, 0.f) + hv.z;
                v.w = fmaxf(hi.y * sc.w + sh.w, 0.f) + hv.w;
                *(float4*)&hio[(size_t)n * H + kq] = v;
            } else {
                v = *(const float4*)&A[(size_t)n * H + kq];
            }
        }
        __half2 a = __floats2half2_rn(v.x, v.y);
        __half2 b = __floats2half2_rn(v.z, v.w);
        *(uint2*)&Ah[row * 136 + kq] = make_uint2(*(unsigned*)&a, *(unsigned*)&b);
    }
    __syncthreads();

    const int wave = tid >> 6;
    const int lane = tid & 63;
    const int lrow = lane & 15;
    const int lgrp = lane >> 4;

    f16x8 bf[4][2];
#pragma unroll
    for (int ks = 0; ks < 4; ks++)
#pragma unroll
        for (int nt = 0; nt < 2; nt++) {
            int nb = wave * 2 + nt;
            bf[ks][nt] = *(const f16x8*)&wfrag[(((ks * 8 + nb) * 64 + lane) << 3)];
        }

    f32x4 acc[4][2];
#pragma unroll
    for (int mt = 0; mt < 4; mt++)
#pragma unroll
        for (int nt = 0; nt < 2; nt++) acc[mt][nt] = (f32x4){0.f, 0.f, 0.f, 0.f};

#pragma unroll
    for (int ks = 0; ks < 4; ks++) {
#pragma unroll
        for (int mt = 0; mt < 4; mt++) {
            f16x8 af = *(const f16x8*)&Ah[(mt * 16 + lrow) * 136 + ks * 32 + lgrp * 8];
            acc[mt][0] = __builtin_amdgcn_mfma_f32_16x16x32_f16(af, bf[ks][0], acc[mt][0], 0, 0, 0);
            acc[mt][1] = __builtin_amdgcn_mfma_f32_16x16x32_f16(af, bf[ks][1], acc[mt][1], 0, 0, 0);
        }
    }

    const int col0 = wave * 32 + lrow;
    const int col1 = col0 + 16;
    float b0 = bias ? bias[col0] : 0.f;
    float b1 = bias ? bias[col1] : 0.f;
    float aS0 = 0.f, aS1 = 0.f, aD0 = 0.f, aD1 = 0.f;
    if (sS) {
        aS0 = attS[col0]; aS1 = attS[col1];
        aD0 = attD[col0]; aD1 = attD[col1];
    }

#pragma unroll
    for (int mt = 0; mt < 4; mt++) {
#pragma unroll
        for (int reg = 0; reg < 4; reg++) {
            int row = rowBase + mt * 16 + lgrp * 4 + reg;
            float v0 = acc[mt][0][reg] + b0;
            float v1 = acc[mt][1][reg] + b1;
            if (row < Nrows) {
                if (out16) {
                    out16[(size_t)row * H + col0] = __float2half(v0);
                    out16[(size_t)row * H + col1] = __float2half(v1);
                } else {
                    out32[(size_t)row * H + col0] = v0;
                    out32[(size_t)row * H + col1] = v1;
                }
            }
            if (sS) {
                float ps = v0 * aS0 + v1 * aS1;
                float pd = v0 * aD0 + v1 * aD1;
#pragma unroll
                for (int off = 8; off >= 1; off >>= 1) {
                    ps += __shfl_xor(ps, off, 16);
                    pd += __shfl_xor(pd, off, 16);
                }
                if (lrow == 0 && row < Nrows) {
                    sS[row * 4 + wave] = ps;
                    sD[row * 4 + wave] = pd;
                }
            }
        }
    }
}

// ---------------------------------------------------------------------------
// Fused noise-prediction head, fully MFMA (z1, z2, out); single Ah buffer.
// ---------------------------------------------------------------------------
__global__ __launch_bounds__(256) void np_fused_mfma(
    const float* __restrict__ nf, const int* __restrict__ batch,
    const float* __restrict__ tgW, const __half* __restrict__ wnp,
    const float* __restrict__ npb2, const float* __restrict__ npb3,
    float* __restrict__ out, int Nrows)
{
    __shared__ __half Ah[64 * 136];
    const int tid = threadIdx.x;
    const int rowBase = blockIdx.x * 64;

    for (int idx = tid; idx < 64 * 32; idx += 256) {
        int row = idx >> 5;
        int kq = (idx & 31) * 4;
        int n = rowBase + row;
        float4 v = make_float4(0.f, 0.f, 0.f, 0.f);
        if (n < Nrows) v = *(const float4*)&nf[(size_t)n * H + kq];
        __half2 a = __floats2half2_rn(v.x, v.y);
        __half2 b = __floats2half2_rn(v.z, v.w);
        *(uint2*)&Ah[row * 136 + kq] = make_uint2(*(unsigned*)&a, *(unsigned*)&b);
    }
    __syncthreads();

    const int wave = tid >> 6;
    const int lane = tid & 63;
    const int lrow = lane & 15;
    const int lgrp = lane >> 4;

    f32x4 acc[4][2];

    // ---- GEMM1 (MFMA): z1 = nf @ W1 ----
    {
        f16x8 bf[4][2];
#pragma unroll
        for (int ks = 0; ks < 4; ks++)
#pragma unroll
            for (int nt = 0; nt < 2; nt++) {
                int nb = wave * 2 + nt;
                bf[ks][nt] = *(const f16x8*)&wnp[(((ks * 8 + nb) * 64 + lane) << 3)];
            }
#pragma unroll
        for (int mt = 0; mt < 4; mt++)
#pragma unroll
            for (int nt = 0; nt < 2; nt++) acc[mt][nt] = (f32x4){0.f, 0.f, 0.f, 0.f};
#pragma unroll
        for (int ks = 0; ks < 4; ks++) {
#pragma unroll
            for (int mt = 0; mt < 4; mt++) {
                f16x8 af = *(const f16x8*)&Ah[(mt * 16 + lrow) * 136 + ks * 32 + lgrp * 8];
                acc[mt][0] = __builtin_amdgcn_mfma_f32_16x16x32_f16(af, bf[ks][0], acc[mt][0], 0, 0, 0);
                acc[mt][1] = __builtin_amdgcn_mfma_f32_16x16x32_f16(af, bf[ks][1], acc[mt][1], 0, 0, 0);
            }
        }
    }
    __syncthreads();   // all GEMM1 A-reads done

    // epilogue1: z1 = silu(acc + tgW[batch[n]][col]) -> Ah row-major
#pragma unroll
    for (int mt = 0; mt < 4; mt++) {
#pragma unroll
        for (int nt = 0; nt < 2; nt++) {
            int col = wave * 32 + nt * 16 + lrow;
#pragma unroll
            for (int reg = 0; reg < 4; reg++) {
                int row = mt * 16 + lgrp * 4 + reg;
                int n = rowBase + row;
                float v = acc[mt][nt][reg];
                if (n < Nrows) v += tgW[(size_t)batch[n] * H + col];
                Ah[row * 136 + col] = __float2half(silu_f(v));
            }
        }
    }
    __syncthreads();

    // ---- GEMM2 (MFMA): z2 = z1 @ W2 ----
    {
        const __half* w2 = wnp + 16384;
        f16x8 bf[4][2];
#pragma unroll
        for (int ks = 0; ks < 4; ks++)
#pragma unroll
            for (int nt = 0; nt < 2; nt++) {
                int nb = wave * 2 + nt;
                bf[ks][nt] = *(const f16x8*)&w2[(((ks * 8 + nb) * 64 + lane) << 3)];
            }
#pragma unroll
        for (int mt = 0; mt < 4; mt++)
#pragma unroll
            for (int nt = 0; nt < 2; nt++) acc[mt][nt] = (f32x4){0.f, 0.f, 0.f, 0.f};
#pragma unroll
        for (int ks = 0; ks < 4; ks++) {
#pragma unroll
            for (int mt = 0; mt < 4; mt++) {
                f16x8 af = *(const f16x8*)&Ah[(mt * 16 + lrow) * 136 + ks * 32 + lgrp * 8];
                acc[mt][0] = __builtin_amdgcn_mfma_f32_16x16x32_f16(af, bf[ks][0], acc[mt][0], 0, 0, 0);
                acc[mt][1] = __builtin_amdgcn_mfma_f32_16x16x32_f16(af, bf[ks][1], acc[mt][1], 0, 0, 0);
            }
        }
    }
    __syncthreads();   // all GEMM2 A-reads done before overwrite

    // epilogue2: z2 = silu(acc + b2) -> Ah row-major (reuse)
#pragma unroll
    for (int mt = 0; mt < 4; mt++) {
#pragma unroll
        for (int nt = 0; nt < 2; nt++) {
            int col = wave * 32 + nt * 16 + lrow;
            float b2 = npb2[col];
#pragma unroll
            for (int reg = 0; reg < 4; reg++) {
                int row = mt * 16 + lgrp * 4 + reg;
                Ah[row * 136 + col] = __float2half(silu_f(acc[mt][nt][reg] + b2));
            }
        }
    }
    __syncthreads();

    // ---- GEMM3 (MFMA): out[64,48-pad] = z2 @ W3pad; wave owns 16 rows x 48 cols
    {
        const __half* w3 = wnp + 32768;
        f32x4 acc3[3];
#pragma unroll
        for (int nt = 0; nt < 3; nt++) acc3[nt] = (f32x4){0.f, 0.f, 0.f, 0.f};
#pragma unroll
        for (int ks = 0; ks < 4; ks++) {
            f16x8 af = *(const f16x8*)&Ah[(wave * 16 + lrow) * 136 + ks * 32 + lgrp * 8];
#pragma unroll
            for (int nt = 0; nt < 3; nt++) {
                f16x8 bf = *(const f16x8*)&w3[(((ks * 3 + nt) * 64 + lane) << 3)];
                acc3[nt] = __builtin_amdgcn_mfma_f32_16x16x32_f16(af, bf, acc3[nt], 0, 0, 0);
            }
        }
#pragma unroll
        for (int nt = 0; nt < 3; nt++) {
            int col = nt * 16 + lrow;
            if (col < AD) {
                float b3 = npb3[col];
#pragma unroll
                for (int reg = 0; reg < 4; reg++) {
                    int row = rowBase + wave * 16 + lgrp * 4 + reg;
                    if (row < Nrows) out[(size_t)row * AD + col] = acc3[nt][reg] + b3;
                }
            }
        }
    }
}

// ---------------------------------------------------------------------------
// CSR build
// ---------------------------------------------------------------------------
__global__ __launch_bounds__(256) void hist_dst(const int* __restrict__ edge_index,
                                                int* __restrict__ deg)
{
    int e = blockIdx.x * 256 + threadIdx.x;
    if (e < N_EDGES) atomicAdd(&deg[edge_index[N_EDGES + e]], 1);
}

__global__ __launch_bounds__(256) void scan_part(const int* __restrict__ cnt,
                                                 int* __restrict__ bsum, int n)
{
    int tid = threadIdx.x;
    int i0 = blockIdx.x * 1024 + tid * 4;
    int s = 0;
#pragma unroll
    for (int j = 0; j < 4; j++) if (i0 + j < n) s += cnt[i0 + j];
    __shared__ int red[256];
    red[tid] = s;
    __syncthreads();
    for (int off = 128; off >= 1; off >>= 1) {
        if (tid < off) red[tid] += red[tid + off];
        __syncthreads();
    }
    if (tid == 0) bsum[blockIdx.x] = red[0];
}

__global__ __launch_bounds__(256) void scan_tops(const int* __restrict__ bsum,
                                                 int* __restrict__ boff, int G,
                                                 int* __restrict__ total)
{
    int tid = threadIdx.x;
    int v = (tid < G) ? bsum[tid] : 0;
    __shared__ int ps[256];
    ps[tid] = v;
    __syncthreads();
    for (int off = 1; off < 256; off <<= 1) {
        int t = (tid >= off) ? ps[tid - off] : 0;
        __syncthreads();
        ps[tid] += t;
        __syncthreads();
    }
    if (tid < G) boff[tid] = ps[tid] - v;
    if (tid == 255) *total = ps[255];
}

// scan_final also emits gcur[b] = csr_ptr[b*256] (bucket base cursors).
__global__ __launch_bounds__(256) void scan_final(const int* __restrict__ cnt,
                                                  const int* __restrict__ boff,
                                                  int* __restrict__ ptr,
                                                  int* __restrict__ gcur, int n)
{
    int tid = threadIdx.x;
    int i0 = blockIdx.x * 1024 + tid * 4;
    int v[4];
#pragma unroll
    for (int j = 0; j < 4; j++) v[j] = (i0 + j < n) ? cnt[i0 + j] : 0;
    int s = v[0] + v[1] + v[2] + v[3];
    __shared__ int ps[256];
    ps[tid] = s;
    __syncthreads();
    for (int off = 1; off < 256; off <<= 1) {
        int t = (tid >= off) ? ps[tid - off] : 0;
        __syncthreads();
        ps[tid] += t;
        __syncthreads();
    }
    int run = boff[blockIdx.x] + ps[tid] - s;
    if ((i0 & 255) == 0 && (i0 >> 8) < NBUCK && i0 < n) gcur[i0 >> 8] = run;
#pragma unroll
    for (int j = 0; j < 4; j++) {
        if (i0 + j < n) { ptr[i0 + j] = run; run += v[j]; }
    }
}

// ---------------------------------------------------------------------------
// Bucketed scatter pass A
// ---------------------------------------------------------------------------
__global__ __launch_bounds__(256) void bucket_scatter_a(
    const int* __restrict__ edge_index, int* __restrict__ gcur,
    int4* __restrict__ tmp)
{
    __shared__ int cnt[NBUCK], cbase[NBUCK], cur[NBUCK];
    const int tid = threadIdx.x;
    const int e0 = blockIdx.x * EPB;
    for (int i = tid; i < NBUCK; i += 256) { cnt[i] = 0; cur[i] = 0; }
    __syncthreads();
    for (int i = 0; i < EPB; i += 256) {
        int e = e0 + i + tid;
        if (e < N_EDGES) atomicAdd(&cnt[edge_index[N_EDGES + e] >> 8], 1);
    }
    __syncthreads();
    for (int i = tid; i < NBUCK; i += 256)
        if (cnt[i] > 0) cbase[i] = atomicAdd(&gcur[i], cnt[i]);
    __syncthreads();
    for (int i = 0; i < EPB; i += 256) {
        int e = e0 + i + tid;
        if (e < N_EDGES) {
            int s = edge_index[e];
            int d = edge_index[N_EDGES + e];
            int b = d >> 8;
            int off = atomicAdd(&cur[b], 1);
            tmp[cbase[b] + off] = make_int4(s, e, d, 0);
        }
    }
}

// Pass B: block = bucket; LDS per-node cursors; local scatter to csr_se.
__global__ __launch_bounds__(256) void bucket_scatter_b(
    const int4* __restrict__ tmp, const int* __restrict__ csr_ptr,
    int2* __restrict__ csr_se)
{
    __shared__ int lcur[256];
    const int b = blockIdx.x;
    const int n0 = b << 8;
    const int tid = threadIdx.x;
    lcur[tid] = 0;
    __syncthreads();
    int start = csr_ptr[n0];
    int end   = csr_ptr[min(n0 + 256, N_NODES)];
    for (int p = start + tid; p < end; p += 256) {
        int4 q = tmp[p];
        int pos = atomicAdd(&lcur[q.z - n0], 1);
        csr_se[csr_ptr[q.z] + pos] = make_int2(q.x, q.y);
    }
}

// ---------------------------------------------------------------------------
// se3[l][p][hh] = edge_attr[e(p)] @ M_l[:,hh] + c_l[hh]  (all 3 layers, once)
// ---------------------------------------------------------------------------
__global__ __launch_bounds__(256) void se3_pre(
    const int2* __restrict__ csr_se, const float* __restrict__ edge_attr,
    const float* __restrict__ mc, __half* __restrict__ se3)
{
    __shared__ float Ml[LAYERS * 44];
    int tid = threadIdx.x;
    if (tid < LAYERS * 44) Ml[tid] = mc[tid];
    __syncthreads();
    int p = blockIdx.x * 256 + tid;
    if (p >= N_EDGES) return;
    int e = csr_se[p].y;
    float ea[BD];
    const float* eap = &edge_attr[(size_t)e * BD];
#pragma unroll
    for (int j = 0; j < BD; j++) ea[j] = eap[j];
#pragma unroll
    for (int l = 0; l < LAYERS; l++) {
        const float* M = &Ml[l * 44];
        float s0 = M[40], s1 = M[41], s2 = M[42], s3 = M[43];
#pragma unroll
        for (int j = 0; j < BD; j++) {
            float x = ea[j];
            s0 += x * M[j * 4 + 0]; s1 += x * M[j * 4 + 1];
            s2 += x * M[j * 4 + 2]; s3 += x * M[j * 4 + 3];
        }
        __half2 h01 = __floats2half2_rn(s0, s1);
        __half2 h23 = __floats2half2_rn(s2, s3);
        uint2 u = make_uint2(*(const unsigned*)&h01, *(const unsigned*)&h23);
        *(uint2*)&se3[((size_t)l * N_EDGES + p) * 4] = u;
    }
}

// ---------------------------------------------------------------------------
// GAT aggregation (r22 v1 structure, no-max softmax).
// ---------------------------------------------------------------------------
__global__ __launch_bounds__(256) void gat_agg_full(
    const __half* __restrict__ xh16, const __half* __restrict__ se3l,
    const float* __restrict__ sS,
    const int* __restrict__ csr_ptr, const int2* __restrict__ csr_se,
    const float* __restrict__ sD, const float* __restrict__ conv_b_l,
    __half* __restrict__ agg)
{
    int n = (blockIdx.x * 256 + threadIdx.x) >> 6;
    if (n >= N_NODES) return;
    int lane = threadIdx.x & 63;
    int c0 = lane * 2;
    int hd = lane >> 4;
    int start = csr_ptr[n], end = csr_ptr[n + 1];
    float sDn = sD[n * 4 + hd];

    float d_run = 0.f;
    float acc0 = 0.f, acc1 = 0.f;

    for (int base = start; base < end; base += 64) {
        int cnt = min(64, end - base);
        int s_l = (lane < cnt) ? (csr_se[base + lane].x << 7) : 0;

        float e_t[4];
        float dsum = 0.f;
#pragma unroll
        for (int t = 0; t < 4; t++) {
            int i = (lane & 15) + t * 16;
            float e = 0.f;
            if (i < cnt) {
                int src7 = __shfl(s_l, i);
                float a = sS[(src7 >> 5) + hd] +
                    __half2float(se3l[(size_t)(base + i) * 4 + hd]) + sDn;
                a = (a >= 0.f) ? a : 0.2f * a;
                e = __expf(a);
            }
            e_t[t] = e;
            dsum += e;
        }
#pragma unroll
        for (int off = 8; off >= 1; off >>= 1)
            dsum += __shfl_xor(dsum, off, 16);
        d_run += dsum;

        int srcb = lane & 48;
#pragma unroll
        for (int t = 0; t < 4; t++) {
            int rem = cnt - t * 16;
            if (rem <= 0) break;
            int lim = min(16, (rem + 3) & ~3);
            for (int i2 = 0; i2 < lim; i2 += 4) {
                int i = t * 16 + i2;
                int s0 = __shfl(s_l, i + 0), s1 = __shfl(s_l, i + 1);
                int s2 = __shfl(s_l, i + 2), s3 = __shfl(s_l, i + 3);
                float w0 = __shfl(e_t[t], srcb | (i2 + 0));
                float w1 = __shfl(e_t[t], srcb | (i2 + 1));
                float w2 = __shfl(e_t[t], srcb | (i2 + 2));
                float w3 = __shfl(e_t[t], srcb | (i2 + 3));
                float2 x0 = __half22float2(*(const __half2*)&xh16[s0 + c0]);
                float2 x1 = __half22float2(*(const __half2*)&xh16[s1 + c0]);
                float2 x2 = __half22float2(*(const __half2*)&xh16[s2 + c0]);
                float2 x3 = __half22float2(*(const __half2*)&xh16[s3 + c0]);
                acc0 += x0.x * w0 + x1.x * w1 + x2.x * w2 + x3.x * w3;
                acc1 += x0.y * w0 + x1.y * w1 + x2.y * w2 + x3.y * w3;
            }
        }
    }
    float inv = 1.f / (d_run + 1e-16f);
    __half2 o = __floats2half2_rn(acc0 * inv + conv_b_l[c0],
                                  acc1 * inv + conv_b_l[c0 + 1]);
    *(__half2*)&agg[(size_t)n * H + c0] = o;
}

// ---------------------------------------------------------------------------
// BatchNorm partials: 512 blocks x 256 thr; coalesced 4-half loads.
// ---------------------------------------------------------------------------
__global__ __launch_bounds__(256) void bn_partial_f(const __half* __restrict__ agg,
                                                    float* __restrict__ part)
{
    const int PER = (N_NODES + 511) / 512;   // 98
    __shared__ float red[2][8][128];
    int b = blockIdx.x;
    int cg = threadIdx.x & 31;
    int rs = threadIdx.x >> 5;   // 0..7
    int c4 = cg * 4;
    int s = b * PER, e = min(N_NODES, s + PER);
    float s0 = 0.f, s1 = 0.f, s2 = 0.f, s3 = 0.f;
    float q0 = 0.f, q1 = 0.f, q2 = 0.f, q3 = 0.f;
    for (int n = s + rs; n < e; n += 8) {
        uint2 u = *(const uint2*)&agg[(size_t)n * H + c4];
        float2 lo = __half22float2(*(__half2*)&u.x);
        float2 hi = __half22float2(*(__half2*)&u.y);
        s0 += lo.x; q0 += lo.x * lo.x;
        s1 += lo.y; q1 += lo.y * lo.y;
        s2 += hi.x; q2 += hi.x * hi.x;
        s3 += hi.y; q3 += hi.y * hi.y;
    }
    *(float4*)&red[0][rs][c4] = make_float4(s0, s1, s2, s3);
    *(float4*)&red[1][rs][c4] = make_float4(q0, q1, q2, q3);
    __syncthreads();
    if (threadIdx.x < 128) {
        int c = threadIdx.x;
        float sum = 0.f, sq = 0.f;
#pragma unroll
        for (int r = 0; r < 8; r++) { sum += red[0][r][c]; sq += red[1][r][c]; }
        part[b * H + c] = sum;
        part[512 * H + b * H + c] = sq;
    }
}

__global__ __launch_bounds__(256) void bn_finish_f(const float* __restrict__ part,
                                                   const float* __restrict__ gamma,
                                                   const float* __restrict__ beta,
                                                   float* __restrict__ scale,
                                                   float* __restrict__ shift)
{
    __shared__ double red[2][2][128];
    int c = threadIdx.x & 127;
    int g = threadIdx.x >> 7;
    double s = 0.0, q = 0.0;
    for (int b = g * 256; b < (g + 1) * 256; b++) {
        s += (double)part[b * H + c];
        q += (double)part[512 * H + b * H + c];
    }
    red[0][g][c] = s;
    red[1][g][c] = q;
    __syncthreads();
    if (g == 0) {
        s = red[0][0][c] + red[0][1][c];
        q = red[1][0][c] + red[1][1][c];
        float mu = (float)(s / N_NODES);
        float var = (float)(q / N_NODES) - mu * mu;
        float rstd = rsqrtf(var + 1e-5f);
        float sc = gamma[c] * rstd;
        scale[c] = sc;
        shift[c] = beta[c] - mu * sc;
    }
}

// ---------------------------------------------------------------------------
// Graph head MLP with fused mean-pool (block g, 4 thread-quarters).
// ---------------------------------------------------------------------------
__global__ __launch_bounds__(512) void graph_head_mlp(
    const int* __restrict__ gptr, const float* __restrict__ nf,
    const float* __restrict__ t_emb,
    const float* __restrict__ pW1, const float* __restrict__ pb1,
    const float* __restrict__ pW2, const float* __restrict__ pb2,
    const float* __restrict__ npW1, const float* __restrict__ npb1,
    float* __restrict__ tgW)
{
    int g = blockIdx.x;
    int c = threadIdx.x & 127;
    int q = threadIdx.x >> 7;
    __shared__ float row[H], z[H];
    __shared__ float red[4][H];

    int s = gptr[g], e = gptr[g + 1];
    float cf = (e - s > 0) ? (float)(e - s) : 1.f;
    int qlen = (e - s + 3) >> 2;
    int qs = s + q * qlen;
    int qe = min(e, qs + qlen);
    float sum = 0.f;
    for (int n = qs; n < qe; n++) sum += nf[(size_t)n * H + c];
    red[q][c] = sum;
    __syncthreads();
    if (q == 0) row[c] = (red[0][c] + red[1][c] + red[2][c] + red[3][c]) / cf;
    __syncthreads();

    float p = 0.f;
#pragma unroll 8
    for (int k = q * 32; k < q * 32 + 32; k++) p += row[k] * pW1[k * H + c];
    red[q][c] = p;
    __syncthreads();
    if (q == 0) z[c] = silu_f(red[0][c] + red[1][c] + red[2][c] + red[3][c] + pb1[c]);
    __syncthreads();

    p = 0.f;
#pragma unroll 8
    for (int k = q * 32; k < q * 32 + 32; k++) p += z[k] * pW2[k * H + c];
    red[q][c] = p;
    __syncthreads();
    if (q == 0) row[c] = red[0][c] + red[1][c] + red[2][c] + red[3][c] + pb2[c]
                         + t_emb[g * H + c];
    __syncthreads();

    p = 0.f;
#pragma unroll 8
    for (int k = q * 32; k < q * 32 + 32; k++)
        p += row[k] * npW1[(size_t)(128 + k) * H + c];
    red[q][c] = p;
    __syncthreads();
    if (q == 0) tgW[g * H + c] = red[0][c] + red[1][c] + red[2][c] + red[3][c] + npb1[c];
}

// ---------------------------------------------------------------------------
extern "C" void kernel_launch(void* const* d_in, const int* in_sizes, int n_in,
                              void* d_out, int out_size, void* d_ws, size_t ws_size,
                              hipStream_t stream)
{
    const float* x          = (const float*)d_in[0];
    const int*   edge_index = (const int*)d_in[1];
    const float* edge_attr  = (const float*)d_in[2];
    const int*   batch      = (const int*)d_in[3];
    const int*   t          = (const int*)d_in[4];
    const float* atom_W     = (const float*)d_in[5];
    const float* atom_b     = (const float*)d_in[6];
    const float* bond_W     = (const float*)d_in[7];
    const float* bond_b     = (const float*)d_in[8];
    const float* lin_W      = (const float*)d_in[9];
    const float* edge_W     = (const float*)d_in[10];
    const float* att_src    = (const float*)d_in[11];
    const float* att_dst    = (const float*)d_in[12];
    const float* att_edge   = (const float*)d_in[13];
    const float* conv_b     = (const float*)d_in[14];
    const float* bn_gamma   = (const float*)d_in[15];
    const float* bn_beta    = (const float*)d_in[16];
    const float* out_W      = (const float*)d_in[17];
    const float* out_b      = (const float*)d_in[18];
    const float* time_W1    = (const float*)d_in[19];
    const float* time_b1    = (const float*)d_in[20];
    const float* time_W2    = (const float*)d_in[21];
    const float* time_b2    = (const float*)d_in[22];
    const float* pool_W1    = (const float*)d_in[23];
    const float* pool_b1    = (const float*)d_in[24];
    const float* pool_W2    = (const float*)d_in[25];
    const float* pool_b2    = (const float*)d_in[26];
    const float* np_W1      = (const float*)d_in[27];
    const float* np_b1      = (const float*)d_in[28];
    const float* np_W2      = (const float*)d_in[29];
    const float* np_b2      = (const float*)d_in[30];
    const float* np_W3      = (const float*)d_in[31];
    const float* np_b3      = (const float*)d_in[32];

    // ---------------- workspace layout (floats) ----------------
    const size_t OFF_H     = 0;
    const size_t OFF_XH    = 6400000;
    const size_t OFF_AGG   = 12800000;
    const size_t OFF_SD    = 17600000;
    const size_t OFF_TEMB  = 17800000;
    const size_t OFF_TGW   = 17832768;
    const size_t OFF_MC    = 17865536;
    const size_t OFF_BNSC  = 17865792;
    const size_t OFF_BNSH  = 17865920;
    const size_t OFF_PART  = 17866048;
    const size_t OFF_SE3   = 17898816;               // half[3][E][4]
    const size_t REQ_FLOATS = 22698816;
    const size_t REQ_BYTES  = REQ_FLOATS * 4;        // 90.8 MB

    if (ws_size < REQ_BYTES) {
        hipMemsetAsync(d_out, 0, (size_t)out_size * sizeof(float), stream);
        return;
    }

    float* fws    = (float*)d_ws;
    float* h      = fws + OFF_H;
    float* xh     = fws + OFF_XH;
    __half* xh16  = (__half*)(fws + OFF_XH);
    int4*  etmp   = (int4*)(fws + OFF_XH);
    __half* agg   = (__half*)(fws + OFF_AGG);
    float* sD     = fws + OFF_SD;
    float* t_emb  = fws + OFF_TEMB;
    float* tgW    = fws + OFF_TGW;
    float* mc     = fws + OFF_MC;
    float* bnsc   = fws + OFF_BNSC;
    float* bnsh   = fws + OFF_BNSH;
    float* part   = fws + OFF_PART;
    __half* wnp   = (__half*)part;
    __half* se3   = (__half*)(fws + OFF_SE3);

    int* ib       = (int*)d_out;
    int* csr_ptr  = ib;
    int2* csr_se  = (int2*)(ib + 50016);
    int* deg      = ib + 1650016;
    int* gptr     = ib + 1700032;
    int* bsum     = ib + 1700292;
    int* boff     = ib + 1700356;
    float* sS     = (float*)d_out + 1700420;
    float* bnpart = sS;
    __half* w16   = (__half*)((float*)d_out + 1900420);  // 65536 halves -> ends 1933188
    int* gcur     = ib + 1933188;                        // 196 ints (no aliasing)

    hipMemsetAsync(deg, 0, N_NODES * sizeof(int), stream);

    // merged setup (blocks 0..257) + weight packing (blocks 258..665)
    setup_all<<<NB + 2 + (4 * H * H + 2 * H * H + H * 48 + 255) / 256, 256, 0, stream>>>(
        edge_W, att_edge, bond_W, bond_b, mc,
        batch, gptr, t, time_W1, time_b1, time_W2, time_b2, t_emb,
        lin_W, out_W, np_W1, np_W2, np_W3, w16, wnp);

    hist_dst<<<(N_EDGES + 255) / 256, 256, 0, stream>>>(edge_index, deg);

    const int GSN = (N_NODES + 1023) / 1024;
    scan_part<<<GSN, 256, 0, stream>>>(deg, bsum, N_NODES);
    scan_tops<<<1, 256, 0, stream>>>(bsum, boff, GSN, &csr_ptr[N_NODES]);
    scan_final<<<GSN, 256, 0, stream>>>(deg, boff, csr_ptr, gcur, N_NODES);

    bucket_scatter_a<<<(N_EDGES + EPB - 1) / EPB, 256, 0, stream>>>(
        edge_index, gcur, etmp);
    bucket_scatter_b<<<NBUCK, 256, 0, stream>>>(etmp, csr_ptr, csr_se);

    const int GB = (N_NODES + 63) / 64;
    const int GE = (N_EDGES + 255) / 256;

    se3_pre<<<GE, 256, 0, stream>>>(csr_se, edge_attr, mc, se3);

    gemm128<AD><<<GB, 256, 0, stream>>>(x, atom_W, atom_b, h, N_NODES, H);

    for (int l = 0; l < LAYERS; l++) {
        gemm_mfma_bn<<<GB, 256, 0, stream>>>(
            (l == 0) ? h : nullptr,
            (l == 0) ? nullptr : agg, bnsc, bnsh, h,
            w16 + (size_t)l * 16384, nullptr,
            nullptr, xh16,
            att_src + l * H, att_dst + l * H, sS, sD, N_NODES);
        gat_agg_full<<<N_NODES / 4, 256, 0, stream>>>(
            xh16, se3 + (size_t)l * N_EDGES * 4, sS,
            csr_ptr, csr_se, sD, conv_b + l * H, agg);
        bn_partial_f<<<512, 256, 0, stream>>>(agg, bnpart);
        bn_finish_f<<<1, 256, 0, stream>>>(bnpart, bn_gamma + l * H,
                                           bn_beta + l * H, bnsc, bnsh);
    }

    gemm_mfma_bn<<<GB, 256, 0, stream>>>(
        nullptr, agg, bnsc, bnsh, h,
        w16 + (size_t)3 * 16384, out_b,
        xh, nullptr,
        nullptr, nullptr, nullptr, nullptr, N_NODES);

    graph_head_mlp<<<NB, 512, 0, stream>>>(gptr, xh, t_emb, pool_W1, pool_b1,
                                           pool_W2, pool_b2, np_W1, np_b1, tgW);

    np_fused_mfma<<<GB, 256, 0, stream>>>(xh, batch, tgW, wnp, np_b2, np_b3,
                                          (float*)d_out, N_NODES);
}